// Round 1
// 2374.454 us; speedup vs baseline: 1.8109x; 1.8109x over previous
//
#include <hip/hip_runtime.h>
#include <math.h>

#define VV 32000
#define DD 512
#define NLAYER 6
#define BB 2
#define SS 2048
#define HH 8
#define NST 16
#define KC 4
#define DI 1024
#define TOT 2312            // DI + DI + H + H*N + H*N
#define TOTP 2432           // TOT padded up to multiple of 128
#define BS (BB*SS)          // 4096
#define CHUNK 32
#define NCHUNK (SS/CHUNK)   // 64

typedef __attribute__((ext_vector_type(8))) short short8;   // 8 bf16 (4 VGPRs)
typedef __attribute__((ext_vector_type(4))) float f32x4;

// ---------------------------------------------------------------- bf16 helpers
__device__ __forceinline__ unsigned short f2bf(float f) {
    unsigned u = __float_as_uint(f);
    u += 0x7fff + ((u >> 16) & 1);          // round-nearest-even
    return (unsigned short)(u >> 16);
}
__device__ __forceinline__ float bf2f(unsigned short h) {
    return __uint_as_float(((unsigned)h) << 16);
}

__device__ __forceinline__ void gload_lds16(const void* g, void* l) {
    __builtin_amdgcn_global_load_lds((const __attribute__((address_space(1))) void*)g,
                                     (__attribute__((address_space(3))) void*)l,
                                     16, 0, 0);
}

// ---------------------------------------------------------------- fp32 -> bf16 hi/lo split
// rows >= n_real (padded region) are written as zeros.
__global__ void split_kernel(const float* __restrict__ src,
                             unsigned short* __restrict__ hi,
                             unsigned short* __restrict__ lo,
                             int n_real, int n_pad) {
    int idx = (blockIdx.x * blockDim.x + threadIdx.x) * 4;
    if (idx >= n_pad) return;
    float4 v = make_float4(0.f, 0.f, 0.f, 0.f);
    if (idx < n_real) v = *(const float4*)(src + idx);
    float a[4] = {v.x, v.y, v.z, v.w};
    ushort4 hv, lv;
    unsigned short* hp = (unsigned short*)&hv;
    unsigned short* lp = (unsigned short*)&lv;
    #pragma unroll
    for (int j = 0; j < 4; ++j) {
        unsigned short h = f2bf(a[j]);
        hp[j] = h;
        lp[j] = f2bf(a[j] - bf2f(h));
    }
    *(ushort4*)(hi + idx) = hv;
    *(ushort4*)(lo + idx) = lv;
}

// ---------------------------------------------------------------- embed
__global__ void embed_kernel(const int* __restrict__ tokens,
                             const float* __restrict__ embed,
                             float* __restrict__ x) {
    int row = blockIdx.x;
    int tok = tokens[row];
    const float4* src = (const float4*)(embed + (size_t)tok * DD);
    float4* dst = (float4*)(x + (size_t)row * DD);
    dst[threadIdx.x] = src[threadIdx.x];
}

// ---------------------------------------------------------------- rmsnorm -> bf16 hi/lo
__global__ void rmsnorm_kernel(const float* __restrict__ x,
                               const float* __restrict__ w,
                               unsigned short* __restrict__ xh,
                               unsigned short* __restrict__ xl) {
    int row = blockIdx.x;
    int tid = threadIdx.x;  // 256
    const float* xr = x + (size_t)row * DD;
    float a = xr[tid], b = xr[tid + 256];
    float v = a * a + b * b;
    for (int off = 32; off > 0; off >>= 1) v += __shfl_down(v, off, 64);
    __shared__ float wsum[4];
    if ((tid & 63) == 0) wsum[tid >> 6] = v;
    __syncthreads();
    float tot = wsum[0] + wsum[1] + wsum[2] + wsum[3];
    float sc = rsqrtf(tot * (1.0f / DD) + 1e-6f);
    float o0 = a * sc * w[tid];
    float o1 = b * sc * w[tid + 256];
    size_t base = (size_t)row * DD;
    unsigned short h0 = f2bf(o0), h1 = f2bf(o1);
    xh[base + tid]       = h0; xl[base + tid]       = f2bf(o0 - bf2f(h0));
    xh[base + tid + 256] = h1; xl[base + tid + 256] = f2bf(o1 - bf2f(h1));
}

// ---------------------------------------------------------------- MFMA GEMM (NT), bf16x3 split
// C[M,N] = (Ah+Al)[M,K] * (Bh+Bl)[N,K]^T  (+src) (+bias)
// M = 4096 (always multiple of 128); B buffers padded so n-rows always valid.
// 128x128 block tile, BK=32, 4 waves (2x2), each wave 64x64 via 4x4 frags of 16x16x32.
template <int ADD_SRC, int ADD_BIAS>
__global__ __launch_bounds__(256) void gemm_mfma(
        const unsigned short* __restrict__ Ah, const unsigned short* __restrict__ Al,
        const unsigned short* __restrict__ Bh, const unsigned short* __restrict__ Bl,
        const float* __restrict__ src, const float* __restrict__ bias,
        float* __restrict__ C, int N, int Kd)
{
    __shared__ __align__(16) unsigned short As[128 * 32];   // 8 KB, rows of 64B, XOR-swizzled
    __shared__ __align__(16) unsigned short Bs[128 * 32];   // 8 KB
    const int tid  = threadIdx.x;
    const int lane = tid & 63;
    const int w    = tid >> 6;
    const int wr   = w >> 1, wc = w & 1;
    const int m0 = blockIdx.y * 128;
    const int n0 = blockIdx.x * 128;

    f32x4 acc[4][4] = {};

    // --- staging geometry: 512 16B-slots per tile, 2 rounds of 256 threads.
    // LDS is written linearly by global_load_lds (wave-uniform base + lane*16);
    // the swizzle is applied by PRE-SWIZZLING the global source k-group:
    //   LDS slot (row, q) holds global k-group (q ^ (row&3)).
    int s0v = tid, s1v = 256 + tid;
    int row0 = s0v >> 2, row1 = s1v >> 2;
    int q0 = (s0v & 3) ^ (row0 & 3);
    int q1 = (s1v & 3) ^ (row1 & 3);
    char* ldsA0 = (char*)As + (w * 64) * 16;          // wave-uniform bases
    char* ldsA1 = (char*)As + (256 + w * 64) * 16;
    char* ldsB0 = (char*)Bs + (w * 64) * 16;
    char* ldsB1 = (char*)Bs + (256 + w * 64) * 16;

    // --- ds_read addresses (constant across the whole K loop)
    // A frag i: row = wr*64+i*16+(lane&15), k-group = lane>>4 (8 contiguous k's),
    // read at swizzled slot (k-group ^ (row&3)).
    const char* ra[4]; const char* rb[4];
    #pragma unroll
    for (int i = 0; i < 4; ++i) {
        int rrow = wr * 64 + i * 16 + (lane & 15);
        ra[i] = (const char*)As + rrow * 64 + (((lane >> 4) ^ (rrow & 3)) * 16);
        int crow = wc * 64 + i * 16 + (lane & 15);
        rb[i] = (const char*)Bs + crow * 64 + (((lane >> 4) ^ (crow & 3)) * 16);
    }

    #pragma unroll 1
    for (int ph = 0; ph < 3; ++ph) {                 // Ah*Bh + Al*Bh + Ah*Bl
        const unsigned short* pA = (ph == 1) ? Al : Ah;
        const unsigned short* pB = (ph == 2) ? Bl : Bh;
        const unsigned short* gA0 = pA + (size_t)(m0 + row0) * Kd + q0 * 8;
        const unsigned short* gA1 = pA + (size_t)(m0 + row1) * Kd + q1 * 8;
        const unsigned short* gB0 = pB + (size_t)(n0 + row0) * Kd + q0 * 8;
        const unsigned short* gB1 = pB + (size_t)(n0 + row1) * Kd + q1 * 8;
        for (int k0 = 0; k0 < Kd; k0 += 32) {
            gload_lds16(gA0 + k0, ldsA0);
            gload_lds16(gA1 + k0, ldsA1);
            gload_lds16(gB0 + k0, ldsB0);
            gload_lds16(gB1 + k0, ldsB1);
            __syncthreads();                          // compiler drains vmcnt before barrier
            short8 af[4], bf[4];
            #pragma unroll
            for (int i = 0; i < 4; ++i) af[i] = *(const short8*)ra[i];
            #pragma unroll
            for (int j = 0; j < 4; ++j) bf[j] = *(const short8*)rb[j];
            #pragma unroll
            for (int i = 0; i < 4; ++i)
                #pragma unroll
                for (int j = 0; j < 4; ++j)
                    acc[i][j] = __builtin_amdgcn_mfma_f32_16x16x32_bf16(af[i], bf[j], acc[i][j], 0, 0, 0);
            __syncthreads();
        }
    }

    // --- epilogue: C/D layout col = lane&15, row = (lane>>4)*4 + reg
    #pragma unroll
    for (int i = 0; i < 4; ++i) {
        int rbase = m0 + wr * 64 + i * 16 + (lane >> 4) * 4;
        #pragma unroll
        for (int j = 0; j < 4; ++j) {
            int col = n0 + wc * 64 + j * 16 + (lane & 15);
            if (col < N) {
                #pragma unroll
                for (int p2 = 0; p2 < 4; ++p2) {
                    size_t o = (size_t)(rbase + p2) * N + col;
                    float vv = acc[i][j][p2];
                    if (ADD_SRC) vv += src[o];
                    if (ADD_BIAS) vv += bias[col];
                    C[o] = vv;
                }
            }
        }
    }
}

// ------------------------------------------------- conv + silu + head-mean + dt/dA
__global__ void conv_state_kernel(const float* __restrict__ p,
                                  const float* __restrict__ cw,
                                  const float* __restrict__ dtb,
                                  const float* __restrict__ alog,
                                  float* __restrict__ x_in,
                                  float* __restrict__ dtv,
                                  float* __restrict__ dAv) {
    int bs = blockIdx.x;
    int s = bs & (SS - 1);
    int tid = threadIdx.x;  // 256
    const float* prow = p + (size_t)bs * TOT + DI;
    float hacc = 0.f;
    #pragma unroll
    for (int j = 0; j < 4; ++j) {
        int c = tid * 4 + j;
        const float* w = cw + c * KC;
        float v = w[3] * prow[c];
        if (s >= 1) v += w[2] * prow[c - TOT];
        if (s >= 2) v += w[1] * prow[c - 2 * TOT];
        if (s >= 3) v += w[0] * prow[c - 3 * TOT];
        float sv = v / (1.f + expf(-v));
        hacc += sv;
    }
    for (int off = 16; off > 0; off >>= 1) hacc += __shfl_down(hacc, off, 32);
    __shared__ float hs[HH];
    if ((tid & 31) == 0) hs[tid >> 5] = hacc;
    __syncthreads();
    if (tid < HH) {
        x_in[(size_t)bs * HH + tid] = hs[tid] * (1.f / 128.f);
        float raw = p[(size_t)bs * TOT + 2 * DI + tid] + dtb[tid];
        float dt = (raw > 20.f) ? raw : log1pf(expf(raw));
        float A = -expf(alog[tid]);
        dtv[(size_t)bs * HH + tid] = dt;
        dAv[(size_t)bs * HH + tid] = expf(dt * A);
    }
}

// ---------------------------------------------------------------- chunked scan
__global__ void scan_phaseA(const float* __restrict__ p,
                            const float* __restrict__ x_in,
                            const float* __restrict__ dtv,
                            const float* __restrict__ dAv,
                            float* __restrict__ carryP,
                            float* __restrict__ hend) {
    int wid = blockIdx.x;
    int cg = wid & (NCHUNK / 4 - 1);
    int bh = wid / (NCHUNK / 4);
    int b = bh >> 3, h = bh & 7;
    int lane = threadIdx.x;
    int csub = lane >> 4, n = lane & 15;
    int chunk = cg * 4 + csub;
    int s0 = chunk * CHUNK;
    float hn = 0.f, P = 1.f;
    const float* pB = p + 2 * DI + HH + h * NST + n;
    for (int t = 0; t < CHUNK; ++t) {
        int idx = b * SS + s0 + t;
        float da = dAv[(size_t)idx * HH + h];
        float u = dtv[(size_t)idx * HH + h] * x_in[(size_t)idx * HH + h] * pB[(size_t)idx * TOT];
        hn = fmaf(da, hn, u);
        P *= da;
    }
    hend[((size_t)bh * NCHUNK + chunk) * NST + n] = hn;
    if (n == 0) carryP[(size_t)bh * NCHUNK + chunk] = P;
}

__global__ void scan_phaseB(const float* __restrict__ carryP,
                            const float* __restrict__ hend,
                            float* __restrict__ hstart) {
    int t = threadIdx.x;
    int bh = t >> 4, n = t & 15;
    float hc = 0.f;
    for (int c = 0; c < NCHUNK; ++c) {
        size_t base = (size_t)bh * NCHUNK + c;
        hstart[base * NST + n] = hc;
        hc = carryP[base] * hc + hend[base * NST + n];
    }
}

__global__ void scan_phaseC(const float* __restrict__ p,
                            const float* __restrict__ x_in,
                            const float* __restrict__ dtv,
                            const float* __restrict__ dAv,
                            const float* __restrict__ hstart,
                            float* __restrict__ y) {
    int wid = blockIdx.x;
    int cg = wid & (NCHUNK / 4 - 1);
    int bh = wid / (NCHUNK / 4);
    int b = bh >> 3, h = bh & 7;
    int lane = threadIdx.x;
    int csub = lane >> 4, n = lane & 15;
    int chunk = cg * 4 + csub;
    int s0 = chunk * CHUNK;
    float hn = hstart[((size_t)bh * NCHUNK + chunk) * NST + n];
    const float* pB = p + 2 * DI + HH + h * NST + n;
    const float* pC = pB + HH * NST;
    for (int t = 0; t < CHUNK; ++t) {
        int idx = b * SS + s0 + t;
        float da = dAv[(size_t)idx * HH + h];
        float u = dtv[(size_t)idx * HH + h] * x_in[(size_t)idx * HH + h] * pB[(size_t)idx * TOT];
        hn = fmaf(da, hn, u);
        float contrib = hn * pC[(size_t)idx * TOT];
        for (int off = 8; off > 0; off >>= 1) contrib += __shfl_down(contrib, off, 16);
        if (n == 0) y[(size_t)idx * HH + h] = contrib;
    }
}

// ---------------------------------------------------------------- y-proj + silu(z) gate -> bf16 hi/lo
__global__ void gate_kernel(const float* __restrict__ p,
                            const float* __restrict__ y,
                            const float* __restrict__ yw,
                            unsigned short* __restrict__ gh,
                            unsigned short* __restrict__ gl) {
    int bs = blockIdx.x;
    int tid = threadIdx.x;  // 256
    __shared__ float ys[HH];
    if (tid < HH) ys[tid] = y[(size_t)bs * HH + tid];
    __syncthreads();
    const float* prow = p + (size_t)bs * TOT;
    float outv[4];
    #pragma unroll
    for (int j = 0; j < 4; ++j) {
        int i = tid * 4 + j;
        const float* wv = yw + i * HH;
        float yd = 0.f;
        #pragma unroll
        for (int h = 0; h < HH; ++h) yd = fmaf(ys[h], wv[h], yd);
        float z = prow[i];
        float sz = z / (1.f + expf(-z));
        outv[j] = yd * sz;
    }
    ushort4 hv, lv;
    unsigned short* hp = (unsigned short*)&hv;
    unsigned short* lp = (unsigned short*)&lv;
    #pragma unroll
    for (int j = 0; j < 4; ++j) {
        unsigned short h = f2bf(outv[j]);
        hp[j] = h;
        lp[j] = f2bf(outv[j] - bf2f(h));
    }
    *(ushort4*)(gh + (size_t)bs * DI + tid * 4) = hv;
    *(ushort4*)(gl + (size_t)bs * DI + tid * 4) = lv;
}

// ---------------------------------------------------------------- final layernorm -> bf16 hi/lo
__global__ void layernorm_kernel(const float* __restrict__ x,
                                 const float* __restrict__ w,
                                 const float* __restrict__ bbias,
                                 unsigned short* __restrict__ oh,
                                 unsigned short* __restrict__ ol) {
    int row = blockIdx.x;
    int tid = threadIdx.x;  // 256
    const float* xr = x + (size_t)row * DD;
    float a = xr[tid], c = xr[tid + 256];
    float sum = a + c;
    for (int off = 32; off > 0; off >>= 1) sum += __shfl_down(sum, off, 64);
    __shared__ float w1[4];
    __shared__ float w2[4];
    if ((tid & 63) == 0) w1[tid >> 6] = sum;
    __syncthreads();
    float mu = (w1[0] + w1[1] + w1[2] + w1[3]) * (1.0f / DD);
    float da = a - mu, dc = c - mu;
    float v = da * da + dc * dc;
    for (int off = 32; off > 0; off >>= 1) v += __shfl_down(v, off, 64);
    if ((tid & 63) == 0) w2[tid >> 6] = v;
    __syncthreads();
    float var = (w2[0] + w2[1] + w2[2] + w2[3]) * (1.0f / DD);
    float sc = rsqrtf(var + 1e-5f);
    float o0 = da * sc * w[tid] + bbias[tid];
    float o1 = dc * sc * w[tid + 256] + bbias[tid + 256];
    size_t base = (size_t)row * DD;
    unsigned short h0 = f2bf(o0), h1 = f2bf(o1);
    oh[base + tid]       = h0; ol[base + tid]       = f2bf(o0 - bf2f(h0));
    oh[base + tid + 256] = h1; ol[base + tid + 256] = f2bf(o1 - bf2f(h1));
}

// ---------------------------------------------------------------- launch
extern "C" void kernel_launch(void* const* d_in, const int* in_sizes, int n_in,
                              void* d_out, int out_size, void* d_ws, size_t ws_size,
                              hipStream_t stream) {
    const int*   tokens   = (const int*)d_in[0];
    const float* embed    = (const float*)d_in[1];
    const float* rms_w    = (const float*)d_in[2];
    const float* in_proj  = (const float*)d_in[3];
    const float* conv_w   = (const float*)d_in[4];
    const float* dt_bias  = (const float*)d_in[5];
    const float* A_log    = (const float*)d_in[6];
    const float* y_proj   = (const float*)d_in[7];
    const float* out_proj = (const float*)d_in[8];
    const float* ln_w     = (const float*)d_in[9];
    const float* ln_b     = (const float*)d_in[10];
    const float* head_w   = (const float*)d_in[11];
    const float* head_b   = (const float*)d_in[12];
    float* out = (float*)d_out;

    float* ws = (float*)d_ws;
    size_t off = 0;
    float* x      = ws + off; off += (size_t)BS * DD;
    float* p      = ws + off; off += (size_t)BS * TOT;
    float* x_in   = ws + off; off += (size_t)BS * HH;
    float* dtv    = ws + off; off += (size_t)BS * HH;
    float* dAv    = ws + off; off += (size_t)BS * HH;
    float* y      = ws + off; off += (size_t)BS * HH;
    float* carryP = ws + off; off += (size_t)BB * HH * NCHUNK;
    float* hend   = ws + off; off += (size_t)BB * HH * NCHUNK * NST;
    float* hstart = ws + off; off += (size_t)BB * HH * NCHUNK * NST;
    unsigned short* xnh = (unsigned short*)(ws + off); off += (size_t)BS * DD / 2;
    unsigned short* xnl = (unsigned short*)(ws + off); off += (size_t)BS * DD / 2;
    unsigned short* gh  = (unsigned short*)(ws + off); off += (size_t)BS * DI / 2;
    unsigned short* gl  = (unsigned short*)(ws + off); off += (size_t)BS * DI / 2;
    unsigned short* wih = (unsigned short*)(ws + off); off += (size_t)NLAYER * TOTP * DD / 2;
    unsigned short* wil = (unsigned short*)(ws + off); off += (size_t)NLAYER * TOTP * DD / 2;
    unsigned short* woh = (unsigned short*)(ws + off); off += (size_t)NLAYER * DD * DI / 2;
    unsigned short* wol = (unsigned short*)(ws + off); off += (size_t)NLAYER * DD * DI / 2;
    unsigned short* whh = (unsigned short*)(ws + off); off += (size_t)VV * DD / 2;
    unsigned short* whl = (unsigned short*)(ws + off); off += (size_t)VV * DD / 2;
    // total ~180 MB of workspace

    // ---- one-time (per launch) weight splits to bf16 hi/lo
    for (int l = 0; l < NLAYER; ++l)
        split_kernel<<<TOTP * DD / 1024, 256, 0, stream>>>(
            in_proj + (size_t)l * TOT * DD,
            wih + (size_t)l * TOTP * DD, wil + (size_t)l * TOTP * DD,
            TOT * DD, TOTP * DD);
    split_kernel<<<NLAYER * DD * DI / 1024, 256, 0, stream>>>(
            out_proj, woh, wol, NLAYER * DD * DI, NLAYER * DD * DI);
    split_kernel<<<VV * DD / 1024, 256, 0, stream>>>(
            head_w, whh, whl, VV * DD, VV * DD);

    embed_kernel<<<BS, 128, 0, stream>>>(tokens, embed, x);

    for (int l = 0; l < NLAYER; ++l) {
        rmsnorm_kernel<<<BS, 256, 0, stream>>>(x, rms_w + l * DD, xnh, xnl);

        dim3 g1(TOTP / 128, BS / 128);
        gemm_mfma<0, 0><<<g1, 256, 0, stream>>>(xnh, xnl,
            wih + (size_t)l * TOTP * DD, wil + (size_t)l * TOTP * DD,
            nullptr, nullptr, p, TOT, DD);

        conv_state_kernel<<<BS, 256, 0, stream>>>(p, conv_w + l * DI * KC,
                                                  dt_bias + l * HH, A_log + l * HH,
                                                  x_in, dtv, dAv);

        scan_phaseA<<<BB * HH * (NCHUNK / 4), 64, 0, stream>>>(p, x_in, dtv, dAv, carryP, hend);
        scan_phaseB<<<1, 256, 0, stream>>>(carryP, hend, hstart);
        scan_phaseC<<<BB * HH * (NCHUNK / 4), 64, 0, stream>>>(p, x_in, dtv, dAv, hstart, y);

        gate_kernel<<<BS, 256, 0, stream>>>(p, y, y_proj + (size_t)l * DI * HH, gh, gl);

        dim3 g2(DD / 128, BS / 128);
        gemm_mfma<1, 0><<<g2, 256, 0, stream>>>(gh, gl,
            woh + (size_t)l * DD * DI, wol + (size_t)l * DD * DI,
            x, nullptr, x, DD, DI);
    }

    layernorm_kernel<<<BS, 256, 0, stream>>>(x, ln_w, ln_b, xnh, xnl);

    dim3 g3(VV / 128, BS / 128);
    gemm_mfma<0, 1><<<g3, 256, 0, stream>>>(xnh, xnl, whh, whl,
        nullptr, head_b, out, VV, DD);
}

// Round 2
// 2023.926 us; speedup vs baseline: 2.1245x; 1.1732x over previous
//
#include <hip/hip_runtime.h>
#include <math.h>

#define VV 32000
#define DD 512
#define NLAYER 6
#define BB 2
#define SS 2048
#define HH 8
#define NST 16
#define KC 4
#define DI 1024
#define TOT 2312            // DI + DI + H + H*N + H*N
#define TOTP 2432           // TOT padded up to multiple of 128
#define BS (BB*SS)          // 4096
#define CHUNK 32
#define NCHUNK (SS/CHUNK)   // 64

typedef __attribute__((ext_vector_type(8))) short short8;   // 8 bf16 (4 VGPRs)
typedef __attribute__((ext_vector_type(4))) float f32x4;

// ---------------------------------------------------------------- bf16 helpers
__device__ __forceinline__ unsigned short f2bf(float f) {
    unsigned u = __float_as_uint(f);
    u += 0x7fff + ((u >> 16) & 1);          // round-nearest-even
    return (unsigned short)(u >> 16);
}
__device__ __forceinline__ float bf2f(unsigned short h) {
    return __uint_as_float(((unsigned)h) << 16);
}

__device__ __forceinline__ void gload_lds16(const void* g, void* l) {
    __builtin_amdgcn_global_load_lds((const __attribute__((address_space(1))) void*)g,
                                     (__attribute__((address_space(3))) void*)l,
                                     16, 0, 0);
}

// ---------------------------------------------------------------- fp32 -> bf16 hi/lo split
__global__ void split_kernel(const float* __restrict__ src,
                             unsigned short* __restrict__ hi,
                             unsigned short* __restrict__ lo,
                             int n_real, int n_pad) {
    int idx = (blockIdx.x * blockDim.x + threadIdx.x) * 4;
    if (idx >= n_pad) return;
    float4 v = make_float4(0.f, 0.f, 0.f, 0.f);
    if (idx < n_real) v = *(const float4*)(src + idx);
    float a[4] = {v.x, v.y, v.z, v.w};
    ushort4 hv, lv;
    unsigned short* hp = (unsigned short*)&hv;
    unsigned short* lp = (unsigned short*)&lv;
    #pragma unroll
    for (int j = 0; j < 4; ++j) {
        unsigned short h = f2bf(a[j]);
        hp[j] = h;
        lp[j] = f2bf(a[j] - bf2f(h));
    }
    *(ushort4*)(hi + idx) = hv;
    *(ushort4*)(lo + idx) = lv;
}

// ---------------------------------------------------------------- embed
__global__ void embed_kernel(const int* __restrict__ tokens,
                             const float* __restrict__ embed,
                             float* __restrict__ x) {
    int row = blockIdx.x;
    int tok = tokens[row];
    const float4* src = (const float4*)(embed + (size_t)tok * DD);
    float4* dst = (float4*)(x + (size_t)row * DD);
    dst[threadIdx.x] = src[threadIdx.x];
}

// ---------------------------------------------------------------- rmsnorm -> bf16 hi/lo
__global__ void rmsnorm_kernel(const float* __restrict__ x,
                               const float* __restrict__ w,
                               unsigned short* __restrict__ xh,
                               unsigned short* __restrict__ xl) {
    int row = blockIdx.x;
    int tid = threadIdx.x;  // 256
    const float* xr = x + (size_t)row * DD;
    float a = xr[tid], b = xr[tid + 256];
    float v = a * a + b * b;
    for (int off = 32; off > 0; off >>= 1) v += __shfl_down(v, off, 64);
    __shared__ float wsum[4];
    if ((tid & 63) == 0) wsum[tid >> 6] = v;
    __syncthreads();
    float tot = wsum[0] + wsum[1] + wsum[2] + wsum[3];
    float sc = rsqrtf(tot * (1.0f / DD) + 1e-6f);
    float o0 = a * sc * w[tid];
    float o1 = b * sc * w[tid + 256];
    size_t base = (size_t)row * DD;
    unsigned short h0 = f2bf(o0), h1 = f2bf(o1);
    xh[base + tid]       = h0; xl[base + tid]       = f2bf(o0 - bf2f(h0));
    xh[base + tid + 256] = h1; xl[base + tid + 256] = f2bf(o1 - bf2f(h1));
}

// ---------------------------------------------------------------- MFMA GEMM (NT), bf16x3 split
// C[M,N] = (Ah+Al)[M,K] * (Bh+Bl)[N,K]^T  (+src) (+bias)
// All 4 tiles (Ah,Al,Bh,Bl) staged ONCE per K-step; 3*MI*NJ MFMAs per barrier pair.
// BK=32 (64B rows). LDS XOR-swizzle: phys q = logical_kg ^ ((row ^ row>>2) & 3)
// -> each 16-lane quarter of a ds_read_b128 hits all 8 bank-groups exactly 2x (free).
// XCD-aware bijective block swizzle, m-fastest so same-XCD neighbors share the B panel.
template <int BM, int BN, int ADD_SRC, int ADD_BIAS>
__global__ __launch_bounds__(256) void gemm_mfma(
        const unsigned short* __restrict__ Ah, const unsigned short* __restrict__ Al,
        const unsigned short* __restrict__ Bh, const unsigned short* __restrict__ Bl,
        const float* __restrict__ src, const float* __restrict__ bias,
        float* __restrict__ C, int M, int N, int Kd)
{
    constexpr int WM = BM / 2, WN = BN / 2;      // per-wave tile (2x2 waves)
    constexpr int MI = WM / 16, NJ = WN / 16;    // frag repeats
    constexpr int ASLOTS = BM * 4;               // 16B slots per A half-tile
    constexpr int BSLOTS = BN * 4;
    constexpr int RA = ASLOTS / 256;             // staging rounds (256 threads)
    constexpr int RB = BSLOTS / 256;
    constexpr int OFF_AH = 0;
    constexpr int OFF_AL = ASLOTS * 16;
    constexpr int OFF_BH = 2 * ASLOTS * 16;
    constexpr int OFF_BL = OFF_BH + BSLOTS * 16;

    __shared__ __align__(16) char lds[(2 * ASLOTS + 2 * BSLOTS) * 16];

    const int tid  = threadIdx.x;
    const int lane = tid & 63;
    const int w    = tid >> 6;
    const int wr   = w >> 1, wc = w & 1;

    // ---- XCD-aware bijective swizzle (grid is 1-D, nwg % 8 == 0 for all call sites)
    int bid = blockIdx.x;
    int nwg = gridDim.x;
    int xcd = bid & 7, lid = bid >> 3;
    int q8 = nwg >> 3, r8 = nwg & 7;
    int wg = (xcd < r8 ? xcd * (q8 + 1) : r8 * (q8 + 1) + (xcd - r8) * q8) + lid;
    int nmb = M / BM;
    int m0 = (wg % nmb) * BM;
    int n0 = (wg / nmb) * BN;

    f32x4 acc[MI][NJ] = {};

    // ---- staging addresses (constant over K loop)
    const unsigned short *gAh[RA], *gAl[RA];
    const unsigned short *gBh[RB], *gBl[RB];
    char *dAh[RA], *dAl[RA], *dBh[RB], *dBl[RB];
    #pragma unroll
    for (int rd = 0; rd < RA; ++rd) {
        int s = rd * 256 + tid;
        int row = s >> 2;
        int qs = (s & 3) ^ ((row ^ (row >> 2)) & 3);
        size_t go = (size_t)(m0 + row) * Kd + qs * 8;
        gAh[rd] = Ah + go; gAl[rd] = Al + go;
        int dslot = (rd * 256 + w * 64) * 16;      // wave-uniform
        dAh[rd] = lds + OFF_AH + dslot;
        dAl[rd] = lds + OFF_AL + dslot;
    }
    #pragma unroll
    for (int rd = 0; rd < RB; ++rd) {
        int s = rd * 256 + tid;
        int row = s >> 2;
        int qs = (s & 3) ^ ((row ^ (row >> 2)) & 3);
        size_t go = (size_t)(n0 + row) * Kd + qs * 8;
        gBh[rd] = Bh + go; gBl[rd] = Bl + go;
        int dslot = (rd * 256 + w * 64) * 16;
        dBh[rd] = lds + OFF_BH + dslot;
        dBl[rd] = lds + OFF_BL + dslot;
    }

    // ---- ds_read addresses (constant over K loop)
    const char *rah[MI], *ral[MI], *rbh[NJ], *rbl[NJ];
    #pragma unroll
    for (int i = 0; i < MI; ++i) {
        int row = wr * WM + i * 16 + (lane & 15);
        int q = (lane >> 4) ^ ((row ^ (row >> 2)) & 3);
        int o = row * 64 + q * 16;
        rah[i] = lds + OFF_AH + o;
        ral[i] = lds + OFF_AL + o;
    }
    #pragma unroll
    for (int j = 0; j < NJ; ++j) {
        int row = wc * WN + j * 16 + (lane & 15);
        int q = (lane >> 4) ^ ((row ^ (row >> 2)) & 3);
        int o = row * 64 + q * 16;
        rbh[j] = lds + OFF_BH + o;
        rbl[j] = lds + OFF_BL + o;
    }

    for (int k0 = 0; k0 < Kd; k0 += 32) {
        #pragma unroll
        for (int rd = 0; rd < RA; ++rd) {
            gload_lds16(gAh[rd] + k0, dAh[rd]);
            gload_lds16(gAl[rd] + k0, dAl[rd]);
        }
        #pragma unroll
        for (int rd = 0; rd < RB; ++rd) {
            gload_lds16(gBh[rd] + k0, dBh[rd]);
            gload_lds16(gBl[rd] + k0, dBl[rd]);
        }
        __syncthreads();
        short8 ah[MI], al[MI], bh[NJ], bl[NJ];
        #pragma unroll
        for (int i = 0; i < MI; ++i) { ah[i] = *(const short8*)rah[i]; al[i] = *(const short8*)ral[i]; }
        #pragma unroll
        for (int j = 0; j < NJ; ++j) { bh[j] = *(const short8*)rbh[j]; bl[j] = *(const short8*)rbl[j]; }
        #pragma unroll
        for (int i = 0; i < MI; ++i)
            #pragma unroll
            for (int j = 0; j < NJ; ++j)
                acc[i][j] = __builtin_amdgcn_mfma_f32_16x16x32_bf16(ah[i], bh[j], acc[i][j], 0, 0, 0);
        #pragma unroll
        for (int i = 0; i < MI; ++i)
            #pragma unroll
            for (int j = 0; j < NJ; ++j)
                acc[i][j] = __builtin_amdgcn_mfma_f32_16x16x32_bf16(al[i], bh[j], acc[i][j], 0, 0, 0);
        #pragma unroll
        for (int i = 0; i < MI; ++i)
            #pragma unroll
            for (int j = 0; j < NJ; ++j)
                acc[i][j] = __builtin_amdgcn_mfma_f32_16x16x32_bf16(ah[i], bl[j], acc[i][j], 0, 0, 0);
        __syncthreads();
    }

    // ---- epilogue: C/D layout col = lane&15, row = (lane>>4)*4 + reg
    #pragma unroll
    for (int i = 0; i < MI; ++i) {
        int rbase = m0 + wr * WM + i * 16 + (lane >> 4) * 4;
        #pragma unroll
        for (int j = 0; j < NJ; ++j) {
            int col = n0 + wc * WN + j * 16 + (lane & 15);
            if (col < N) {
                #pragma unroll
                for (int p2 = 0; p2 < 4; ++p2) {
                    size_t o = (size_t)(rbase + p2) * N + col;
                    float vv = acc[i][j][p2];
                    if (ADD_SRC) vv += src[o];
                    if (ADD_BIAS) vv += bias[col];
                    C[o] = vv;
                }
            }
        }
    }
}

// ------------------------------------------------- conv + silu + head-mean + dt/dA
__global__ void conv_state_kernel(const float* __restrict__ p,
                                  const float* __restrict__ cw,
                                  const float* __restrict__ dtb,
                                  const float* __restrict__ alog,
                                  float* __restrict__ x_in,
                                  float* __restrict__ dtv,
                                  float* __restrict__ dAv) {
    int bs = blockIdx.x;
    int s = bs & (SS - 1);
    int tid = threadIdx.x;  // 256
    const float* prow = p + (size_t)bs * TOT + DI;
    float hacc = 0.f;
    #pragma unroll
    for (int j = 0; j < 4; ++j) {
        int c = tid * 4 + j;
        const float* w = cw + c * KC;
        float v = w[3] * prow[c];
        if (s >= 1) v += w[2] * prow[c - TOT];
        if (s >= 2) v += w[1] * prow[c - 2 * TOT];
        if (s >= 3) v += w[0] * prow[c - 3 * TOT];
        float sv = v / (1.f + expf(-v));
        hacc += sv;
    }
    for (int off = 16; off > 0; off >>= 1) hacc += __shfl_down(hacc, off, 32);
    __shared__ float hs[HH];
    if ((tid & 31) == 0) hs[tid >> 5] = hacc;
    __syncthreads();
    if (tid < HH) {
        x_in[(size_t)bs * HH + tid] = hs[tid] * (1.f / 128.f);
        float raw = p[(size_t)bs * TOT + 2 * DI + tid] + dtb[tid];
        float dt = (raw > 20.f) ? raw : log1pf(expf(raw));
        float A = -expf(alog[tid]);
        dtv[(size_t)bs * HH + tid] = dt;
        dAv[(size_t)bs * HH + tid] = expf(dt * A);
    }
}

// ---------------------------------------------------------------- chunked scan
__global__ void scan_phaseA(const float* __restrict__ p,
                            const float* __restrict__ x_in,
                            const float* __restrict__ dtv,
                            const float* __restrict__ dAv,
                            float* __restrict__ carryP,
                            float* __restrict__ hend) {
    int wid = blockIdx.x;
    int cg = wid & (NCHUNK / 4 - 1);
    int bh = wid / (NCHUNK / 4);
    int b = bh >> 3, h = bh & 7;
    int lane = threadIdx.x;
    int csub = lane >> 4, n = lane & 15;
    int chunk = cg * 4 + csub;
    int s0 = chunk * CHUNK;
    float hn = 0.f, P = 1.f;
    const float* pB = p + 2 * DI + HH + h * NST + n;
    for (int t = 0; t < CHUNK; ++t) {
        int idx = b * SS + s0 + t;
        float da = dAv[(size_t)idx * HH + h];
        float u = dtv[(size_t)idx * HH + h] * x_in[(size_t)idx * HH + h] * pB[(size_t)idx * TOT];
        hn = fmaf(da, hn, u);
        P *= da;
    }
    hend[((size_t)bh * NCHUNK + chunk) * NST + n] = hn;
    if (n == 0) carryP[(size_t)bh * NCHUNK + chunk] = P;
}

__global__ void scan_phaseB(const float* __restrict__ carryP,
                            const float* __restrict__ hend,
                            float* __restrict__ hstart) {
    int t = threadIdx.x;
    int bh = t >> 4, n = t & 15;
    float hc = 0.f;
    for (int c = 0; c < NCHUNK; ++c) {
        size_t base = (size_t)bh * NCHUNK + c;
        hstart[base * NST + n] = hc;
        hc = carryP[base] * hc + hend[base * NST + n];
    }
}

__global__ void scan_phaseC(const float* __restrict__ p,
                            const float* __restrict__ x_in,
                            const float* __restrict__ dtv,
                            const float* __restrict__ dAv,
                            const float* __restrict__ hstart,
                            float* __restrict__ y) {
    int wid = blockIdx.x;
    int cg = wid & (NCHUNK / 4 - 1);
    int bh = wid / (NCHUNK / 4);
    int b = bh >> 3, h = bh & 7;
    int lane = threadIdx.x;
    int csub = lane >> 4, n = lane & 15;
    int chunk = cg * 4 + csub;
    int s0 = chunk * CHUNK;
    float hn = hstart[((size_t)bh * NCHUNK + chunk) * NST + n];
    const float* pB = p + 2 * DI + HH + h * NST + n;
    const float* pC = pB + HH * NST;
    for (int t = 0; t < CHUNK; ++t) {
        int idx = b * SS + s0 + t;
        float da = dAv[(size_t)idx * HH + h];
        float u = dtv[(size_t)idx * HH + h] * x_in[(size_t)idx * HH + h] * pB[(size_t)idx * TOT];
        hn = fmaf(da, hn, u);
        float contrib = hn * pC[(size_t)idx * TOT];
        for (int off = 8; off > 0; off >>= 1) contrib += __shfl_down(contrib, off, 16);
        if (n == 0) y[(size_t)idx * HH + h] = contrib;
    }
}

// ---------------------------------------------------------------- y-proj + silu(z) gate -> bf16 hi/lo
__global__ void gate_kernel(const float* __restrict__ p,
                            const float* __restrict__ y,
                            const float* __restrict__ yw,
                            unsigned short* __restrict__ gh,
                            unsigned short* __restrict__ gl) {
    int bs = blockIdx.x;
    int tid = threadIdx.x;  // 256
    __shared__ float ys[HH];
    if (tid < HH) ys[tid] = y[(size_t)bs * HH + tid];
    __syncthreads();
    const float* prow = p + (size_t)bs * TOT;
    float outv[4];
    #pragma unroll
    for (int j = 0; j < 4; ++j) {
        int i = tid * 4 + j;
        const float* wv = yw + i * HH;
        float yd = 0.f;
        #pragma unroll
        for (int h = 0; h < HH; ++h) yd = fmaf(ys[h], wv[h], yd);
        float z = prow[i];
        float sz = z / (1.f + expf(-z));
        outv[j] = yd * sz;
    }
    ushort4 hv, lv;
    unsigned short* hp = (unsigned short*)&hv;
    unsigned short* lp = (unsigned short*)&lv;
    #pragma unroll
    for (int j = 0; j < 4; ++j) {
        unsigned short h = f2bf(outv[j]);
        hp[j] = h;
        lp[j] = f2bf(outv[j] - bf2f(h));
    }
    *(ushort4*)(gh + (size_t)bs * DI + tid * 4) = hv;
    *(ushort4*)(gl + (size_t)bs * DI + tid * 4) = lv;
}

// ---------------------------------------------------------------- final layernorm -> bf16 hi/lo
__global__ void layernorm_kernel(const float* __restrict__ x,
                                 const float* __restrict__ w,
                                 const float* __restrict__ bbias,
                                 unsigned short* __restrict__ oh,
                                 unsigned short* __restrict__ ol) {
    int row = blockIdx.x;
    int tid = threadIdx.x;  // 256
    const float* xr = x + (size_t)row * DD;
    float a = xr[tid], c = xr[tid + 256];
    float sum = a + c;
    for (int off = 32; off > 0; off >>= 1) sum += __shfl_down(sum, off, 64);
    __shared__ float w1[4];
    __shared__ float w2[4];
    if ((tid & 63) == 0) w1[tid >> 6] = sum;
    __syncthreads();
    float mu = (w1[0] + w1[1] + w1[2] + w1[3]) * (1.0f / DD);
    float da = a - mu, dc = c - mu;
    float v = da * da + dc * dc;
    for (int off = 32; off > 0; off >>= 1) v += __shfl_down(v, off, 64);
    if ((tid & 63) == 0) w2[tid >> 6] = v;
    __syncthreads();
    float var = (w2[0] + w2[1] + w2[2] + w2[3]) * (1.0f / DD);
    float sc = rsqrtf(var + 1e-5f);
    float o0 = da * sc * w[tid] + bbias[tid];
    float o1 = dc * sc * w[tid + 256] + bbias[tid + 256];
    size_t base = (size_t)row * DD;
    unsigned short h0 = f2bf(o0), h1 = f2bf(o1);
    oh[base + tid]       = h0; ol[base + tid]       = f2bf(o0 - bf2f(h0));
    oh[base + tid + 256] = h1; ol[base + tid + 256] = f2bf(o1 - bf2f(h1));
}

// ---------------------------------------------------------------- launch
extern "C" void kernel_launch(void* const* d_in, const int* in_sizes, int n_in,
                              void* d_out, int out_size, void* d_ws, size_t ws_size,
                              hipStream_t stream) {
    const int*   tokens   = (const int*)d_in[0];
    const float* embed    = (const float*)d_in[1];
    const float* rms_w    = (const float*)d_in[2];
    const float* in_proj  = (const float*)d_in[3];
    const float* conv_w   = (const float*)d_in[4];
    const float* dt_bias  = (const float*)d_in[5];
    const float* A_log    = (const float*)d_in[6];
    const float* y_proj   = (const float*)d_in[7];
    const float* out_proj = (const float*)d_in[8];
    const float* ln_w     = (const float*)d_in[9];
    const float* ln_b     = (const float*)d_in[10];
    const float* head_w   = (const float*)d_in[11];
    const float* head_b   = (const float*)d_in[12];
    float* out = (float*)d_out;

    float* ws = (float*)d_ws;
    size_t off = 0;
    float* x      = ws + off; off += (size_t)BS * DD;
    float* p      = ws + off; off += (size_t)BS * TOT;
    float* x_in   = ws + off; off += (size_t)BS * HH;
    float* dtv    = ws + off; off += (size_t)BS * HH;
    float* dAv    = ws + off; off += (size_t)BS * HH;
    float* y      = ws + off; off += (size_t)BS * HH;
    float* carryP = ws + off; off += (size_t)BB * HH * NCHUNK;
    float* hend   = ws + off; off += (size_t)BB * HH * NCHUNK * NST;
    float* hstart = ws + off; off += (size_t)BB * HH * NCHUNK * NST;
    unsigned short* xnh = (unsigned short*)(ws + off); off += (size_t)BS * DD / 2;
    unsigned short* xnl = (unsigned short*)(ws + off); off += (size_t)BS * DD / 2;
    unsigned short* gh  = (unsigned short*)(ws + off); off += (size_t)BS * DI / 2;
    unsigned short* gl  = (unsigned short*)(ws + off); off += (size_t)BS * DI / 2;
    unsigned short* wih = (unsigned short*)(ws + off); off += (size_t)NLAYER * TOTP * DD / 2;
    unsigned short* wil = (unsigned short*)(ws + off); off += (size_t)NLAYER * TOTP * DD / 2;
    unsigned short* woh = (unsigned short*)(ws + off); off += (size_t)NLAYER * DD * DI / 2;
    unsigned short* wol = (unsigned short*)(ws + off); off += (size_t)NLAYER * DD * DI / 2;
    unsigned short* whh = (unsigned short*)(ws + off); off += (size_t)VV * DD / 2;
    unsigned short* whl = (unsigned short*)(ws + off); off += (size_t)VV * DD / 2;

    // ---- one-time (per launch) weight splits to bf16 hi/lo
    for (int l = 0; l < NLAYER; ++l)
        split_kernel<<<TOTP * DD / 1024, 256, 0, stream>>>(
            in_proj + (size_t)l * TOT * DD,
            wih + (size_t)l * TOTP * DD, wil + (size_t)l * TOTP * DD,
            TOT * DD, TOTP * DD);
    split_kernel<<<NLAYER * DD * DI / 1024, 256, 0, stream>>>(
            out_proj, woh, wol, NLAYER * DD * DI, NLAYER * DD * DI);
    split_kernel<<<VV * DD / 1024, 256, 0, stream>>>(
            head_w, whh, whl, VV * DD, VV * DD);

    embed_kernel<<<BS, 128, 0, stream>>>(tokens, embed, x);

    for (int l = 0; l < NLAYER; ++l) {
        rmsnorm_kernel<<<BS, 256, 0, stream>>>(x, rms_w + l * DD, xnh, xnl);

        // in_proj: M=4096, N(tot)=2312 padded 2432 -> grid 32*19 = 608 (div by 8)
        gemm_mfma<128, 128, 0, 0><<<(BS / 128) * (TOTP / 128), 256, 0, stream>>>(
            xnh, xnl,
            wih + (size_t)l * TOTP * DD, wil + (size_t)l * TOTP * DD,
            nullptr, nullptr, p, BS, TOT, DD);

        conv_state_kernel<<<BS, 256, 0, stream>>>(p, conv_w + l * DI * KC,
                                                  dt_bias + l * HH, A_log + l * HH,
                                                  x_in, dtv, dAv);

        scan_phaseA<<<BB * HH * (NCHUNK / 4), 64, 0, stream>>>(p, x_in, dtv, dAv, carryP, hend);
        scan_phaseB<<<1, 256, 0, stream>>>(carryP, hend, hstart);
        scan_phaseC<<<BB * HH * (NCHUNK / 4), 64, 0, stream>>>(p, x_in, dtv, dAv, hstart, y);

        gate_kernel<<<BS, 256, 0, stream>>>(p, y, y_proj + (size_t)l * DI * HH, gh, gl);

        // out_proj: M=4096, N=512, 64x64 tiles -> grid 64*8 = 512 blocks (2/CU)
        gemm_mfma<64, 64, 1, 0><<<(BS / 64) * (DD / 64), 256, 0, stream>>>(
            gh, gl,
            woh + (size_t)l * DD * DI, wol + (size_t)l * DD * DI,
            x, nullptr, x, BS, DD, DI);
    }

    layernorm_kernel<<<BS, 256, 0, stream>>>(x, ln_w, ln_b, xnh, xnl);

    // head: M=4096, N=32000 -> grid 32*250 = 8000 (div by 8)
    gemm_mfma<128, 128, 0, 1><<<(BS / 128) * (VV / 128), 256, 0, stream>>>(
        xnh, xnl, whh, whl,
        nullptr, head_b, out, BS, VV, DD);
}